// Round 3
// baseline (21489.790 us; speedup 1.0000x reference)
//
#include <hip/hip_runtime.h>
#include <hip/hip_bf16.h>
#include <cstdint>

#define TB 16
#define TT 16384
#define TI 64
#define TH 128
#define TG 512  // 4*H

__device__ __forceinline__ float sigf(float z) {
    return 1.0f / (1.0f + __expf(-z));
}
__device__ __forceinline__ float tanhf_fast(float z) {
    return 2.0f / (1.0f + __expf(-2.0f * z)) - 1.0f;
}
__device__ __forceinline__ float4 ld4(const float* p) {
    return *reinterpret_cast<const float4*>(p);
}
__device__ __forceinline__ void fma4(float4& acc, const float4 w, const float4 h) {
    acc.x = fmaf(w.x, h.x, acc.x);
    acc.y = fmaf(w.y, h.y, acc.y);
    acc.z = fmaf(w.z, h.z, acc.z);
    acc.w = fmaf(w.w, h.w, acc.w);
}
__device__ __forceinline__ float hsum4(const float4 a) {
    return (a.x + a.y) + (a.z + a.w);
}
// Make v opaque so the register allocator cannot rematerialize the load that
// produced it (forces true register residency across the 16384-step loop).
__device__ __forceinline__ void pin4(float4& v) {
    asm volatile("" : "+v"(v.x), "+v"(v.y), "+v"(v.z), "+v"(v.w));
}

// ---------------------------------------------------------------------------
// gx = x @ W_ih^T + b_ih + b_hh
// ---------------------------------------------------------------------------
__global__ __launch_bounds__(256, 2) void gx_precompute(
    const float* __restrict__ x, const float* __restrict__ W_ih,
    const float* __restrict__ b_ih, const float* __restrict__ b_hh,
    float* __restrict__ gx)
{
    const int tid  = threadIdx.x;
    const int j    = tid & (TH - 1);
    const int pair = tid >> 7;
    const int row_a = pair * 2 * TH + j;
    const int row_b = row_a + TH;

    float4 ua[TI / 4], ub[TI / 4];
#pragma unroll
    for (int k4 = 0; k4 < TI / 4; ++k4) {
        ua[k4] = ld4(W_ih + (size_t)row_a * TI + k4 * 4);
        ub[k4] = ld4(W_ih + (size_t)row_b * TI + k4 * 4);
    }
    const float bias_a = b_ih[row_a] + b_hh[row_a];
    const float bias_b = b_ih[row_b] + b_hh[row_b];

    __shared__ __align__(16) float xs[2][TI];
    const int ROWS = 128;
    const size_t r0 = (size_t)blockIdx.x * ROWS;

    if (tid < TI / 4)
        *reinterpret_cast<float4*>(&xs[0][tid * 4]) = ld4(x + r0 * TI + tid * 4);
    __syncthreads();
    float4 xreg = make_float4(0.f, 0.f, 0.f, 0.f);
    if (tid < TI / 4) xreg = ld4(x + (r0 + 1) * TI + tid * 4);

#pragma unroll 1
    for (int rr = 0; rr < ROWS; ++rr) {
        const float* xrow = xs[rr & 1];
        float4 aa = make_float4(0.f, 0.f, 0.f, 0.f);
        float4 ab = make_float4(0.f, 0.f, 0.f, 0.f);
#pragma unroll
        for (int k4 = 0; k4 < TI / 4; ++k4) {
            const float4 x4 = *reinterpret_cast<const float4*>(&xrow[k4 * 4]);
            fma4(aa, ua[k4], x4);
            fma4(ab, ub[k4], x4);
        }
        if (tid < TI / 4) {
            if (rr + 1 < ROWS)
                *reinterpret_cast<float4*>(&xs[(rr + 1) & 1][tid * 4]) = xreg;
            if (rr + 2 < ROWS) xreg = ld4(x + (r0 + rr + 2) * TI + tid * 4);
        }
        float* grow = gx + (r0 + rr) * (size_t)TG;
        grow[row_a] = hsum4(aa) + bias_a;
        grow[row_b] = hsum4(ab) + bias_b;

        asm volatile("s_waitcnt lgkmcnt(0)" ::: "memory");
        __builtin_amdgcn_s_barrier();
    }
}

// ---------------------------------------------------------------------------
// Sequential LSTM scan. One block per batch element. 512 threads.
// Thread tid owns gate row tid (one 128-long dot product, weights pinned in
// 128 VGPRs). gate = tid>>7 : 0=i, 1=f, 2=g, 3=o (wave-uniform).
// ---------------------------------------------------------------------------
template <int FUSED>
__global__ __launch_bounds__(512, 2) void lstm_scan(
    const float* __restrict__ x, const float* __restrict__ W_ih,
    const float* __restrict__ W_hh, const float* __restrict__ b_ih,
    const float* __restrict__ b_hh, const float* __restrict__ gx,
    float* __restrict__ y, float* __restrict__ hn, float* __restrict__ cn)
{
    const int b    = blockIdx.x;
    const int tid  = threadIdx.x;          // gate row 0..511
    const int j    = tid & (TH - 1);
    const int gate = tid >> 7;             // wave-uniform

    __shared__ __align__(16) float h_lds[TH];
    __shared__ __align__(16) float g_lds[TG];
    __shared__ __align__(16) float xs[2][TI];   // FUSED only

    // one W_hh row in registers: 128 f32 = 32 float4 = 128 VGPRs, pinned
    float4 w[TH / 4];
#pragma unroll
    for (int k4 = 0; k4 < TH / 4; ++k4)
        w[k4] = ld4(W_hh + (size_t)tid * TH + k4 * 4);
#pragma unroll
    for (int k4 = 0; k4 < TH / 4; ++k4) pin4(w[k4]);

    float4 u[TI / 4];
    float bias = 0.f;
    if (FUSED) {
#pragma unroll
        for (int k4 = 0; k4 < TI / 4; ++k4)
            u[k4] = ld4(W_ih + (size_t)tid * TI + k4 * 4);
#pragma unroll
        for (int k4 = 0; k4 < TI / 4; ++k4) pin4(u[k4]);
        bias = b_ih[tid] + b_hh[tid];
    }

    if (tid < TH) h_lds[tid] = 0.0f;
    float c_state = 0.0f;
    float h_keep  = 0.0f;

    // gx prefetch (2 steps ahead)
    float  g_c = 0.f, g_n = 0.f;
    float4 xreg = make_float4(0.f, 0.f, 0.f, 0.f);
    const float* gp = gx ? (gx + ((size_t)b * TT + 2) * TG) : nullptr;
    const float* xp = x + ((size_t)b * TT + 2) * TI;
    float* yp = y + (size_t)b * TT * TH;

    if (FUSED) {
        if (tid < TI / 4)
            *reinterpret_cast<float4*>(&xs[0][tid * 4]) =
                ld4(x + ((size_t)b * TT + 0) * TI + tid * 4);
    } else {
        const float* g0 = gx + ((size_t)b * TT) * TG;
        g_c = g0[tid];
        g_n = g0[TG + tid];
    }
    __syncthreads();
    if (FUSED && tid < TI / 4)
        xreg = ld4(x + ((size_t)b * TT + 1) * TI + tid * 4);

#pragma unroll 1
    for (int t = 0; t < TT; ++t) {
        // ---- gate pre-activation: 128-long dot, 2 independent acc chains
        float4 acc0 = make_float4(0.f, 0.f, 0.f, 0.f);
        float4 acc1 = make_float4(0.f, 0.f, 0.f, 0.f);
#pragma unroll
        for (int k4 = 0; k4 < TH / 4; k4 += 2) {
            const float4 h0 = *reinterpret_cast<const float4*>(&h_lds[k4 * 4]);
            const float4 h1 = *reinterpret_cast<const float4*>(&h_lds[k4 * 4 + 4]);
            fma4(acc0, w[k4], h0);
            fma4(acc1, w[k4 + 1], h1);
        }
        float p = hsum4(acc0) + hsum4(acc1);
        if (FUSED) {
            float4 fx0 = make_float4(0.f, 0.f, 0.f, 0.f);
            const float* xrow = xs[t & 1];
#pragma unroll
            for (int k4 = 0; k4 < TI / 4; ++k4) {
                const float4 x4 = *reinterpret_cast<const float4*>(&xrow[k4 * 4]);
                fma4(fx0, u[k4], x4);
            }
            p += hsum4(fx0) + bias;
        } else {
            p += g_c;
        }

        // ---- activation (gate is wave-uniform; no divergence) ----
        const float act = (gate == 2) ? tanhf_fast(p) : sigf(p);
        g_lds[tid] = act;

        asm volatile("s_waitcnt lgkmcnt(0)" ::: "memory");
        __builtin_amdgcn_s_barrier();

        // ---- state update: threads 0..127 (waves 0,1) ----
        if (tid < TH) {
            const float gi = g_lds[j];
            const float gf = g_lds[TH + j];
            const float gg = g_lds[2 * TH + j];
            const float go = g_lds[3 * TH + j];
            c_state = fmaf(gf, c_state, gi * gg);
            h_keep  = go * tanhf_fast(c_state);
            h_lds[j] = h_keep;
            yp[(size_t)t * TH + j] = h_keep;
        }

        // ---- prefetch for t+2 ----
        if (FUSED) {
            if (tid < TI / 4) {
                if (t + 1 < TT)
                    *reinterpret_cast<float4*>(&xs[(t + 1) & 1][tid * 4]) = xreg;
                if (t + 2 < TT) xreg = ld4(xp + tid * 4);
            }
            xp += TI;
        } else {
            g_c = g_n;
            if (t + 2 < TT) {
                g_n = gp[tid];
                gp += TG;
            }
        }

        asm volatile("s_waitcnt lgkmcnt(0)" ::: "memory");
        __builtin_amdgcn_s_barrier();
    }

    if (tid < TH) {
        hn[(size_t)b * TH + j] = h_keep;
        cn[(size_t)b * TH + j] = c_state;
    }
}

// ---------------------------------------------------------------------------
// BatchNorm over flattened [B*T, H] + LeakyReLU
// ---------------------------------------------------------------------------
__global__ void bn_zero(float* ws) { ws[threadIdx.x] = 0.0f; }

__global__ __launch_bounds__(256) void bn_stats(const float* __restrict__ y,
                                                float* __restrict__ ws)
{
    const int tid  = threadIdx.x;
    const int col4 = tid & 31;
    const int rg   = tid >> 5;
    const int NROW = TB * TT;
    float4 s = make_float4(0.f, 0.f, 0.f, 0.f);
    float4 q = make_float4(0.f, 0.f, 0.f, 0.f);
    for (int row = blockIdx.x * 8 + rg; row < NROW; row += gridDim.x * 8) {
        const float4 v = ld4(y + (size_t)row * TH + col4 * 4);
        s.x += v.x; s.y += v.y; s.z += v.z; s.w += v.w;
        q.x = fmaf(v.x, v.x, q.x); q.y = fmaf(v.y, v.y, q.y);
        q.z = fmaf(v.z, v.z, q.z); q.w = fmaf(v.w, v.w, q.w);
    }
    __shared__ float4 ls[256], lq[256];
    ls[tid] = s; lq[tid] = q;
    __syncthreads();
    if (tid < 32) {
        float4 S = ls[tid], Q = lq[tid];
        for (int g2 = 1; g2 < 8; ++g2) {
            const float4 a = ls[g2 * 32 + tid], b2 = lq[g2 * 32 + tid];
            S.x += a.x; S.y += a.y; S.z += a.z; S.w += a.w;
            Q.x += b2.x; Q.y += b2.y; Q.z += b2.z; Q.w += b2.w;
        }
        atomicAdd(&ws[tid * 4 + 0], S.x); atomicAdd(&ws[tid * 4 + 1], S.y);
        atomicAdd(&ws[tid * 4 + 2], S.z); atomicAdd(&ws[tid * 4 + 3], S.w);
        atomicAdd(&ws[TH + tid * 4 + 0], Q.x); atomicAdd(&ws[TH + tid * 4 + 1], Q.y);
        atomicAdd(&ws[TH + tid * 4 + 2], Q.z); atomicAdd(&ws[TH + tid * 4 + 3], Q.w);
    }
}

__global__ __launch_bounds__(256) void bn_apply(float* __restrict__ y,
                                                const float* __restrict__ ws,
                                                const float* __restrict__ gamma,
                                                const float* __restrict__ beta)
{
    const int tid  = threadIdx.x;
    const int col4 = tid & 31;
    const int rg   = tid >> 5;
    const int NROW = TB * TT;
    const float invN = 1.0f / (float)(TB * TT);

    const float4 sm = ld4(ws + col4 * 4);
    const float4 sq = ld4(ws + TH + col4 * 4);
    const float4 gm = ld4(gamma + col4 * 4);
    const float4 bt = ld4(beta + col4 * 4);
    float4 mean, scale, shift;
    mean.x = sm.x * invN; mean.y = sm.y * invN;
    mean.z = sm.z * invN; mean.w = sm.w * invN;
    scale.x = rsqrtf(fmaf(-mean.x, mean.x, sq.x * invN) + 1e-5f) * gm.x;
    scale.y = rsqrtf(fmaf(-mean.y, mean.y, sq.y * invN) + 1e-5f) * gm.y;
    scale.z = rsqrtf(fmaf(-mean.z, mean.z, sq.z * invN) + 1e-5f) * gm.z;
    scale.w = rsqrtf(fmaf(-mean.w, mean.w, sq.w * invN) + 1e-5f) * gm.w;
    shift.x = bt.x - mean.x * scale.x; shift.y = bt.y - mean.y * scale.y;
    shift.z = bt.z - mean.z * scale.z; shift.w = bt.w - mean.w * scale.w;

    for (int row = blockIdx.x * 8 + rg; row < NROW; row += gridDim.x * 8) {
        float* p = y + (size_t)row * TH + col4 * 4;
        float4 v = *reinterpret_cast<const float4*>(p);
        v.x = fmaf(v.x, scale.x, shift.x); v.y = fmaf(v.y, scale.y, shift.y);
        v.z = fmaf(v.z, scale.z, shift.z); v.w = fmaf(v.w, scale.w, shift.w);
        v.x = fmaxf(v.x, 0.01f * v.x); v.y = fmaxf(v.y, 0.01f * v.y);
        v.z = fmaxf(v.z, 0.01f * v.z); v.w = fmaxf(v.w, 0.01f * v.w);
        *reinterpret_cast<float4*>(p) = v;
    }
}

// ---------------------------------------------------------------------------
extern "C" void kernel_launch(void* const* d_in, const int* in_sizes, int n_in,
                              void* d_out, int out_size, void* d_ws, size_t ws_size,
                              hipStream_t stream)
{
    const float* x     = (const float*)d_in[0];
    const float* W_ih  = (const float*)d_in[1];
    const float* W_hh  = (const float*)d_in[2];
    const float* b_ih  = (const float*)d_in[3];
    const float* b_hh  = (const float*)d_in[4];
    const float* gamma = (const float*)d_in[5];
    const float* beta  = (const float*)d_in[6];

    float* y  = (float*)d_out;
    float* hn = y + (size_t)TB * TT * TH;
    float* cn = hn + TB * TH;

    float* ws_stats = (float*)d_ws;
    const size_t GX_BYTES = (size_t)TB * TT * TG * sizeof(float);
    const bool use_ws = ws_size >= GX_BYTES + 4096;

    bn_zero<<<1, 256, 0, stream>>>(ws_stats);

    if (use_ws) {
        float* gxbuf = (float*)((char*)d_ws + 4096);
        gx_precompute<<<2048, 256, 0, stream>>>(x, W_ih, b_ih, b_hh, gxbuf);
        lstm_scan<0><<<TB, 512, 0, stream>>>(x, W_ih, W_hh, b_ih, b_hh, gxbuf,
                                             y, hn, cn);
    } else {
        lstm_scan<1><<<TB, 512, 0, stream>>>(x, W_ih, W_hh, b_ih, b_hh, nullptr,
                                             y, hn, cn);
    }

    bn_stats<<<512, 256, 0, stream>>>(y, ws_stats);
    bn_apply<<<2048, 256, 0, stream>>>(y, ws_stats, gamma, beta);
}

// Round 4
// 19372.321 us; speedup vs baseline: 1.1093x; 1.1093x over previous
//
#include <hip/hip_runtime.h>
#include <hip/hip_bf16.h>
#include <cstdint>

#define TB 16
#define TT 16384
#define TI 64
#define TH 128
#define TG 512  // 4*H

__device__ __forceinline__ float sigf(float z) {
    return 1.0f / (1.0f + __expf(-z));
}
__device__ __forceinline__ float tanhf_fast(float z) {
    return 2.0f / (1.0f + __expf(-2.0f * z)) - 1.0f;
}
__device__ __forceinline__ float4 ld4(const float* p) {
    return *reinterpret_cast<const float4*>(p);
}
__device__ __forceinline__ void fma4(float4& acc, const float4 w, const float4 h) {
    acc.x = fmaf(w.x, h.x, acc.x);
    acc.y = fmaf(w.y, h.y, acc.y);
    acc.z = fmaf(w.z, h.z, acc.z);
    acc.w = fmaf(w.w, h.w, acc.w);
}
__device__ __forceinline__ float hsum4(const float4 a) {
    return (a.x + a.y) + (a.z + a.w);
}
// Prevent rematerialization of loaded values (asm-defined values can't be
// re-derived from the original global load).
__device__ __forceinline__ void pin4(float4& v) {
    asm volatile("" : "+v"(v.x), "+v"(v.y), "+v"(v.z), "+v"(v.w));
}

// ---------------------------------------------------------------------------
// gx = x @ W_ih^T + b_ih + b_hh
// ---------------------------------------------------------------------------
__global__ __launch_bounds__(256, 2) void gx_precompute(
    const float* __restrict__ x, const float* __restrict__ W_ih,
    const float* __restrict__ b_ih, const float* __restrict__ b_hh,
    float* __restrict__ gx)
{
    const int tid  = threadIdx.x;
    const int j    = tid & (TH - 1);
    const int pair = tid >> 7;
    const int row_a = pair * 2 * TH + j;
    const int row_b = row_a + TH;

    float4 ua[TI / 4], ub[TI / 4];
#pragma unroll
    for (int k4 = 0; k4 < TI / 4; ++k4) {
        ua[k4] = ld4(W_ih + (size_t)row_a * TI + k4 * 4);
        ub[k4] = ld4(W_ih + (size_t)row_b * TI + k4 * 4);
    }
    const float bias_a = b_ih[row_a] + b_hh[row_a];
    const float bias_b = b_ih[row_b] + b_hh[row_b];

    __shared__ __align__(16) float xs[2][TI];
    const int ROWS = 128;
    const size_t r0 = (size_t)blockIdx.x * ROWS;

    if (tid < TI / 4)
        *reinterpret_cast<float4*>(&xs[0][tid * 4]) = ld4(x + r0 * TI + tid * 4);
    __syncthreads();
    float4 xreg = make_float4(0.f, 0.f, 0.f, 0.f);
    if (tid < TI / 4) xreg = ld4(x + (r0 + 1) * TI + tid * 4);

#pragma unroll 1
    for (int rr = 0; rr < ROWS; ++rr) {
        const float* xrow = xs[rr & 1];
        float4 aa = make_float4(0.f, 0.f, 0.f, 0.f);
        float4 ab = make_float4(0.f, 0.f, 0.f, 0.f);
#pragma unroll
        for (int k4 = 0; k4 < TI / 4; ++k4) {
            const float4 x4 = *reinterpret_cast<const float4*>(&xrow[k4 * 4]);
            fma4(aa, ua[k4], x4);
            fma4(ab, ub[k4], x4);
        }
        if (tid < TI / 4) {
            if (rr + 1 < ROWS)
                *reinterpret_cast<float4*>(&xs[(rr + 1) & 1][tid * 4]) = xreg;
            if (rr + 2 < ROWS) xreg = ld4(x + (r0 + rr + 2) * TI + tid * 4);
        }
        float* grow = gx + (r0 + rr) * (size_t)TG;
        grow[row_a] = hsum4(aa) + bias_a;
        grow[row_b] = hsum4(ab) + bias_b;

        asm volatile("s_waitcnt lgkmcnt(0)" ::: "memory");
        __builtin_amdgcn_s_barrier();
    }
}

// ---------------------------------------------------------------------------
// Sequential LSTM scan. One block per batch element. 512 threads.
// Thread tid owns gate row tid (one 128-long dot product, weights pinned in
// 128 VGPRs). gate = tid>>7 : 0=i, 1=f, 2=g, 3=o (wave-uniform).
// amdgpu_waves_per_eu(2,2): cap occupancy target at 2 waves/SIMD so the RA
// has a 256-VGPR budget and keeps the weight row resident (R2's spill fix).
// ---------------------------------------------------------------------------
template <int FUSED>
__global__
__attribute__((amdgpu_flat_work_group_size(512, 512), amdgpu_waves_per_eu(2, 2)))
void lstm_scan(
    const float* __restrict__ x, const float* __restrict__ W_ih,
    const float* __restrict__ W_hh, const float* __restrict__ b_ih,
    const float* __restrict__ b_hh, const float* __restrict__ gx,
    float* __restrict__ y, float* __restrict__ hn, float* __restrict__ cn)
{
    const int b    = blockIdx.x;
    const int tid  = threadIdx.x;          // gate row 0..511
    const int j    = tid & (TH - 1);
    const int gate = tid >> 7;             // wave-uniform

    __shared__ __align__(16) float h_lds[TH];
    __shared__ __align__(16) float g_lds[TG];
    __shared__ __align__(16) float xs[2][TI];   // FUSED only

    // one W_hh row in registers: 128 f32 = 32 float4 = 128 VGPRs, pinned
    float4 w[TH / 4];
#pragma unroll
    for (int k4 = 0; k4 < TH / 4; ++k4)
        w[k4] = ld4(W_hh + (size_t)tid * TH + k4 * 4);
#pragma unroll
    for (int k4 = 0; k4 < TH / 4; ++k4) pin4(w[k4]);

    float4 u[TI / 4];
    float bias = 0.f;
    if (FUSED) {
#pragma unroll
        for (int k4 = 0; k4 < TI / 4; ++k4)
            u[k4] = ld4(W_ih + (size_t)tid * TI + k4 * 4);
#pragma unroll
        for (int k4 = 0; k4 < TI / 4; ++k4) pin4(u[k4]);
        bias = b_ih[tid] + b_hh[tid];
    }

    if (tid < TH) h_lds[tid] = 0.0f;
    float c_state = 0.0f;
    float h_keep  = 0.0f;

    // gx prefetch (2 steps ahead)
    float  g_c = 0.f, g_n = 0.f;
    float4 xreg = make_float4(0.f, 0.f, 0.f, 0.f);
    const float* gp = gx ? (gx + ((size_t)b * TT + 2) * TG) : nullptr;
    const float* xp = x + ((size_t)b * TT + 2) * TI;
    float* yp = y + (size_t)b * TT * TH;

    if (FUSED) {
        if (tid < TI / 4)
            *reinterpret_cast<float4*>(&xs[0][tid * 4]) =
                ld4(x + ((size_t)b * TT + 0) * TI + tid * 4);
    } else {
        const float* g0 = gx + ((size_t)b * TT) * TG;
        g_c = g0[tid];
        g_n = g0[TG + tid];
    }
    __syncthreads();
    if (FUSED && tid < TI / 4)
        xreg = ld4(x + ((size_t)b * TT + 1) * TI + tid * 4);

#pragma unroll 1
    for (int t = 0; t < TT; ++t) {
        // ---- gate pre-activation: 128-long dot, 2 independent acc chains
        float4 acc0 = make_float4(0.f, 0.f, 0.f, 0.f);
        float4 acc1 = make_float4(0.f, 0.f, 0.f, 0.f);
#pragma unroll
        for (int k4 = 0; k4 < TH / 4; k4 += 2) {
            const float4 h0 = *reinterpret_cast<const float4*>(&h_lds[k4 * 4]);
            const float4 h1 = *reinterpret_cast<const float4*>(&h_lds[k4 * 4 + 4]);
            fma4(acc0, w[k4], h0);
            fma4(acc1, w[k4 + 1], h1);
        }
        float p = hsum4(acc0) + hsum4(acc1);
        if (FUSED) {
            float4 fx0 = make_float4(0.f, 0.f, 0.f, 0.f);
            const float* xrow = xs[t & 1];
#pragma unroll
            for (int k4 = 0; k4 < TI / 4; ++k4) {
                const float4 x4 = *reinterpret_cast<const float4*>(&xrow[k4 * 4]);
                fma4(fx0, u[k4], x4);
            }
            p += hsum4(fx0) + bias;
        } else {
            p += g_c;
        }

        // ---- activation (gate is wave-uniform; no divergence) ----
        const float act = (gate == 2) ? tanhf_fast(p) : sigf(p);
        g_lds[tid] = act;

        asm volatile("s_waitcnt lgkmcnt(0)" ::: "memory");
        __builtin_amdgcn_s_barrier();

        // ---- state update: threads 0..127 (waves 0,1) ----
        if (tid < TH) {
            const float gi = g_lds[j];
            const float gf = g_lds[TH + j];
            const float gg = g_lds[2 * TH + j];
            const float go = g_lds[3 * TH + j];
            c_state = fmaf(gf, c_state, gi * gg);
            h_keep  = go * tanhf_fast(c_state);
            h_lds[j] = h_keep;
            yp[(size_t)t * TH + j] = h_keep;
        }

        // ---- prefetch for t+2 ----
        if (FUSED) {
            if (tid < TI / 4) {
                if (t + 1 < TT)
                    *reinterpret_cast<float4*>(&xs[(t + 1) & 1][tid * 4]) = xreg;
                if (t + 2 < TT) xreg = ld4(xp + tid * 4);
            }
            xp += TI;
        } else {
            g_c = g_n;
            if (t + 2 < TT) {
                g_n = gp[tid];
                gp += TG;
            }
        }

        asm volatile("s_waitcnt lgkmcnt(0)" ::: "memory");
        __builtin_amdgcn_s_barrier();
    }

    if (tid < TH) {
        hn[(size_t)b * TH + j] = h_keep;
        cn[(size_t)b * TH + j] = c_state;
    }
}

// ---------------------------------------------------------------------------
// BatchNorm over flattened [B*T, H] + LeakyReLU
// ---------------------------------------------------------------------------
__global__ void bn_zero(float* ws) { ws[threadIdx.x] = 0.0f; }

__global__ __launch_bounds__(256) void bn_stats(const float* __restrict__ y,
                                                float* __restrict__ ws)
{
    const int tid  = threadIdx.x;
    const int col4 = tid & 31;
    const int rg   = tid >> 5;
    const int NROW = TB * TT;
    float4 s = make_float4(0.f, 0.f, 0.f, 0.f);
    float4 q = make_float4(0.f, 0.f, 0.f, 0.f);
    for (int row = blockIdx.x * 8 + rg; row < NROW; row += gridDim.x * 8) {
        const float4 v = ld4(y + (size_t)row * TH + col4 * 4);
        s.x += v.x; s.y += v.y; s.z += v.z; s.w += v.w;
        q.x = fmaf(v.x, v.x, q.x); q.y = fmaf(v.y, v.y, q.y);
        q.z = fmaf(v.z, v.z, q.z); q.w = fmaf(v.w, v.w, q.w);
    }
    __shared__ float4 ls[256], lq[256];
    ls[tid] = s; lq[tid] = q;
    __syncthreads();
    if (tid < 32) {
        float4 S = ls[tid], Q = lq[tid];
        for (int g2 = 1; g2 < 8; ++g2) {
            const float4 a = ls[g2 * 32 + tid], b2 = lq[g2 * 32 + tid];
            S.x += a.x; S.y += a.y; S.z += a.z; S.w += a.w;
            Q.x += b2.x; Q.y += b2.y; Q.z += b2.z; Q.w += b2.w;
        }
        atomicAdd(&ws[tid * 4 + 0], S.x); atomicAdd(&ws[tid * 4 + 1], S.y);
        atomicAdd(&ws[tid * 4 + 2], S.z); atomicAdd(&ws[tid * 4 + 3], S.w);
        atomicAdd(&ws[TH + tid * 4 + 0], Q.x); atomicAdd(&ws[TH + tid * 4 + 1], Q.y);
        atomicAdd(&ws[TH + tid * 4 + 2], Q.z); atomicAdd(&ws[TH + tid * 4 + 3], Q.w);
    }
}

__global__ __launch_bounds__(256) void bn_apply(float* __restrict__ y,
                                                const float* __restrict__ ws,
                                                const float* __restrict__ gamma,
                                                const float* __restrict__ beta)
{
    const int tid  = threadIdx.x;
    const int col4 = tid & 31;
    const int rg   = tid >> 5;
    const int NROW = TB * TT;
    const float invN = 1.0f / (float)(TB * TT);

    const float4 sm = ld4(ws + col4 * 4);
    const float4 sq = ld4(ws + TH + col4 * 4);
    const float4 gm = ld4(gamma + col4 * 4);
    const float4 bt = ld4(beta + col4 * 4);
    float4 mean, scale, shift;
    mean.x = sm.x * invN; mean.y = sm.y * invN;
    mean.z = sm.z * invN; mean.w = sm.w * invN;
    scale.x = rsqrtf(fmaf(-mean.x, mean.x, sq.x * invN) + 1e-5f) * gm.x;
    scale.y = rsqrtf(fmaf(-mean.y, mean.y, sq.y * invN) + 1e-5f) * gm.y;
    scale.z = rsqrtf(fmaf(-mean.z, mean.z, sq.z * invN) + 1e-5f) * gm.z;
    scale.w = rsqrtf(fmaf(-mean.w, mean.w, sq.w * invN) + 1e-5f) * gm.w;
    shift.x = bt.x - mean.x * scale.x; shift.y = bt.y - mean.y * scale.y;
    shift.z = bt.z - mean.z * scale.z; shift.w = bt.w - mean.w * scale.w;

    for (int row = blockIdx.x * 8 + rg; row < NROW; row += gridDim.x * 8) {
        float* p = y + (size_t)row * TH + col4 * 4;
        float4 v = *reinterpret_cast<const float4*>(p);
        v.x = fmaf(v.x, scale.x, shift.x); v.y = fmaf(v.y, scale.y, shift.y);
        v.z = fmaf(v.z, scale.z, shift.z); v.w = fmaf(v.w, scale.w, shift.w);
        v.x = fmaxf(v.x, 0.01f * v.x); v.y = fmaxf(v.y, 0.01f * v.y);
        v.z = fmaxf(v.z, 0.01f * v.z); v.w = fmaxf(v.w, 0.01f * v.w);
        *reinterpret_cast<float4*>(p) = v;
    }
}

// ---------------------------------------------------------------------------
extern "C" void kernel_launch(void* const* d_in, const int* in_sizes, int n_in,
                              void* d_out, int out_size, void* d_ws, size_t ws_size,
                              hipStream_t stream)
{
    const float* x     = (const float*)d_in[0];
    const float* W_ih  = (const float*)d_in[1];
    const float* W_hh  = (const float*)d_in[2];
    const float* b_ih  = (const float*)d_in[3];
    const float* b_hh  = (const float*)d_in[4];
    const float* gamma = (const float*)d_in[5];
    const float* beta  = (const float*)d_in[6];

    float* y  = (float*)d_out;
    float* hn = y + (size_t)TB * TT * TH;
    float* cn = hn + TB * TH;

    float* ws_stats = (float*)d_ws;
    const size_t GX_BYTES = (size_t)TB * TT * TG * sizeof(float);
    const bool use_ws = ws_size >= GX_BYTES + 4096;

    bn_zero<<<1, 256, 0, stream>>>(ws_stats);

    if (use_ws) {
        float* gxbuf = (float*)((char*)d_ws + 4096);
        gx_precompute<<<2048, 256, 0, stream>>>(x, W_ih, b_ih, b_hh, gxbuf);
        lstm_scan<0><<<TB, 512, 0, stream>>>(x, W_ih, W_hh, b_ih, b_hh, gxbuf,
                                             y, hn, cn);
    } else {
        lstm_scan<1><<<TB, 512, 0, stream>>>(x, W_ih, W_hh, b_ih, b_hh, nullptr,
                                             y, hn, cn);
    }

    bn_stats<<<512, 256, 0, stream>>>(y, ws_stats);
    bn_apply<<<2048, 256, 0, stream>>>(y, ws_stats, gamma, beta);
}

// Round 5
// 10747.304 us; speedup vs baseline: 1.9996x; 1.8025x over previous
//
#include <hip/hip_runtime.h>
#include <hip/hip_bf16.h>
#include <cstdint>

#define TB 16
#define TT 16384
#define TI 64
#define TH 128
#define TG 512  // 4*H

typedef _Float16 half2_t __attribute__((ext_vector_type(2)));

__device__ __forceinline__ float sigf(float z) {
    return 1.0f / (1.0f + __expf(-z));
}
__device__ __forceinline__ float tanhf_fast(float z) {
    return 2.0f / (1.0f + __expf(-2.0f * z)) - 1.0f;
}
__device__ __forceinline__ float4 ld4(const float* p) {
    return *reinterpret_cast<const float4*>(p);
}
__device__ __forceinline__ void fma4(float4& acc, const float4 w, const float4 h) {
    acc.x = fmaf(w.x, h.x, acc.x);
    acc.y = fmaf(w.y, h.y, acc.y);
    acc.z = fmaf(w.z, h.z, acc.z);
    acc.w = fmaf(w.w, h.w, acc.w);
}
__device__ __forceinline__ float hsum4(const float4 a) {
    return (a.x + a.y) + (a.z + a.w);
}
// Prevent rematerialization of a packed fp16 pair.
__device__ __forceinline__ void pin2(half2_t& v) {
    asm volatile("" : "+v"(v));
}

// ---------------------------------------------------------------------------
// gx = x @ W_ih^T + b_ih + b_hh
// ---------------------------------------------------------------------------
__global__ __launch_bounds__(256, 2) void gx_precompute(
    const float* __restrict__ x, const float* __restrict__ W_ih,
    const float* __restrict__ b_ih, const float* __restrict__ b_hh,
    float* __restrict__ gx)
{
    const int tid  = threadIdx.x;
    const int j    = tid & (TH - 1);
    const int pair = tid >> 7;
    const int row_a = pair * 2 * TH + j;
    const int row_b = row_a + TH;

    float4 ua[TI / 4], ub[TI / 4];
#pragma unroll
    for (int k4 = 0; k4 < TI / 4; ++k4) {
        ua[k4] = ld4(W_ih + (size_t)row_a * TI + k4 * 4);
        ub[k4] = ld4(W_ih + (size_t)row_b * TI + k4 * 4);
    }
    const float bias_a = b_ih[row_a] + b_hh[row_a];
    const float bias_b = b_ih[row_b] + b_hh[row_b];

    __shared__ __align__(16) float xs[2][TI];
    const int ROWS = 128;
    const size_t r0 = (size_t)blockIdx.x * ROWS;

    if (tid < TI / 4)
        *reinterpret_cast<float4*>(&xs[0][tid * 4]) = ld4(x + r0 * TI + tid * 4);
    __syncthreads();
    float4 xreg = make_float4(0.f, 0.f, 0.f, 0.f);
    if (tid < TI / 4) xreg = ld4(x + (r0 + 1) * TI + tid * 4);

#pragma unroll 1
    for (int rr = 0; rr < ROWS; ++rr) {
        const float* xrow = xs[rr & 1];
        float4 aa = make_float4(0.f, 0.f, 0.f, 0.f);
        float4 ab = make_float4(0.f, 0.f, 0.f, 0.f);
#pragma unroll
        for (int k4 = 0; k4 < TI / 4; ++k4) {
            const float4 x4 = *reinterpret_cast<const float4*>(&xrow[k4 * 4]);
            fma4(aa, ua[k4], x4);
            fma4(ab, ub[k4], x4);
        }
        if (tid < TI / 4) {
            if (rr + 1 < ROWS)
                *reinterpret_cast<float4*>(&xs[(rr + 1) & 1][tid * 4]) = xreg;
            if (rr + 2 < ROWS) xreg = ld4(x + (r0 + rr + 2) * TI + tid * 4);
        }
        float* grow = gx + (r0 + rr) * (size_t)TG;
        grow[row_a] = hsum4(aa) + bias_a;
        grow[row_b] = hsum4(ab) + bias_b;

        asm volatile("s_waitcnt lgkmcnt(0)" ::: "memory");
        __builtin_amdgcn_s_barrier();
    }
}

// ---------------------------------------------------------------------------
// Sequential LSTM scan, fp16-dot2 version (gx precomputed in ws).
// One block per batch element. 512 threads; thread tid owns gate row tid.
// W_hh row held as 64 packed half2 VGPRs; h broadcast via LDS in fp16.
// gate = tid>>7 : 0=i, 1=f, 2=g, 3=o (wave-uniform).
// ---------------------------------------------------------------------------
__global__
__attribute__((amdgpu_flat_work_group_size(512, 512), amdgpu_waves_per_eu(2, 2)))
void lstm_scan_fp16(
    const float* __restrict__ W_hh, const float* __restrict__ gx,
    float* __restrict__ y, float* __restrict__ hn, float* __restrict__ cn)
{
    const int b    = blockIdx.x;
    const int tid  = threadIdx.x;          // gate row 0..511
    const int j    = tid & (TH - 1);
    const int gate = tid >> 7;             // wave-uniform

    __shared__ __align__(16) half2_t h2_lds[TH / 2];   // h as 64 packed pairs
    __shared__ __align__(16) float   g_lds[TG];

    // W_hh row -> 64 packed half2 (64 VGPRs), pinned against remat
    half2_t wh2[TH / 2];
#pragma unroll
    for (int k = 0; k < TH / 4; ++k) {
        const float4 wv = ld4(W_hh + (size_t)tid * TH + k * 4);
        wh2[2 * k]     = half2_t{(_Float16)wv.x, (_Float16)wv.y};
        wh2[2 * k + 1] = half2_t{(_Float16)wv.z, (_Float16)wv.w};
    }
#pragma unroll
    for (int k = 0; k < TH / 2; ++k) pin2(wh2[k]);

    if (tid < TH / 2) h2_lds[tid] = half2_t{(_Float16)0.f, (_Float16)0.f};
    float c_state = 0.0f;
    float h_keep  = 0.0f;

    // gx prefetch, 3 steps ahead
    const float* gp_base = gx + (size_t)b * TT * TG;
    float g_c  = gp_base[tid];
    float g_n1 = gp_base[TG + tid];
    float g_n2 = gp_base[2 * TG + tid];
    const float* gp = gp_base + 3 * (size_t)TG;
    float* yp = y + (size_t)b * TT * TH;

    __syncthreads();

#pragma unroll 1
    for (int t = 0; t < TT; ++t) {
        // issue prefetch for t+3 early so HBM latency hides under this step
        float g_n3 = 0.f;
        if (t + 3 < TT) g_n3 = gp[tid];
        gp += TG;

        // ---- gate pre-activation: 128-long fp16 dot, 4 f32 acc chains ----
        float a0 = 0.f, a1 = 0.f, a2 = 0.f, a3 = 0.f;
        const float4* hv4 = reinterpret_cast<const float4*>(h2_lds);
#pragma unroll
        for (int k4 = 0; k4 < 16; ++k4) {
            const float4 hv = hv4[k4];   // 8 fp16 of h, broadcast read
            const half2_t h0 = __builtin_bit_cast(half2_t, hv.x);
            const half2_t h1 = __builtin_bit_cast(half2_t, hv.y);
            const half2_t h2 = __builtin_bit_cast(half2_t, hv.z);
            const half2_t h3 = __builtin_bit_cast(half2_t, hv.w);
            a0 = __builtin_amdgcn_fdot2(wh2[4 * k4 + 0], h0, a0, false);
            a1 = __builtin_amdgcn_fdot2(wh2[4 * k4 + 1], h1, a1, false);
            a2 = __builtin_amdgcn_fdot2(wh2[4 * k4 + 2], h2, a2, false);
            a3 = __builtin_amdgcn_fdot2(wh2[4 * k4 + 3], h3, a3, false);
        }
        const float p = ((a0 + a1) + (a2 + a3)) + g_c;

        // ---- activation (gate wave-uniform; no divergence) ----
        const float act = (gate == 2) ? tanhf_fast(p) : sigf(p);
        g_lds[tid] = act;

        asm volatile("s_waitcnt lgkmcnt(0)" ::: "memory");
        __builtin_amdgcn_s_barrier();

        // ---- state update: threads 0..127 (waves 0,1) ----
        if (tid < TH) {
            const float gi = g_lds[j];
            const float gf = g_lds[TH + j];
            const float gg = g_lds[2 * TH + j];
            const float go = g_lds[3 * TH + j];
            c_state = fmaf(gf, c_state, gi * gg);
            h_keep  = go * tanhf_fast(c_state);
            reinterpret_cast<_Float16*>(h2_lds)[j] = (_Float16)h_keep;
            yp[(size_t)t * TH + j] = h_keep;
        }

        // rotate prefetch ring
        g_c = g_n1; g_n1 = g_n2; g_n2 = g_n3;

        asm volatile("s_waitcnt lgkmcnt(0)" ::: "memory");
        __builtin_amdgcn_s_barrier();
    }

    if (tid < TH) {
        hn[(size_t)b * TH + j] = h_keep;
        cn[(size_t)b * TH + j] = c_state;
    }
}

// ---------------------------------------------------------------------------
// Fallback scan (no workspace): f32, recomputes x-projection on the fly.
// Never used when ws is large enough; kept for safety.
// ---------------------------------------------------------------------------
__global__ __launch_bounds__(512, 2) void lstm_scan_fused(
    const float* __restrict__ x, const float* __restrict__ W_ih,
    const float* __restrict__ W_hh, const float* __restrict__ b_ih,
    const float* __restrict__ b_hh,
    float* __restrict__ y, float* __restrict__ hn, float* __restrict__ cn)
{
    const int b    = blockIdx.x;
    const int tid  = threadIdx.x;
    const int j    = tid & (TH - 1);
    const int gate = tid >> 7;

    __shared__ __align__(16) float h_lds[TH];
    __shared__ __align__(16) float g_lds[TG];
    __shared__ __align__(16) float xs[2][TI];

    float4 w[TH / 4];
#pragma unroll
    for (int k4 = 0; k4 < TH / 4; ++k4)
        w[k4] = ld4(W_hh + (size_t)tid * TH + k4 * 4);
    float4 u[TI / 4];
#pragma unroll
    for (int k4 = 0; k4 < TI / 4; ++k4)
        u[k4] = ld4(W_ih + (size_t)tid * TI + k4 * 4);
    const float bias = b_ih[tid] + b_hh[tid];

    if (tid < TH) h_lds[tid] = 0.0f;
    float c_state = 0.0f;
    float h_keep  = 0.0f;

    float4 xreg = make_float4(0.f, 0.f, 0.f, 0.f);
    const float* xp = x + ((size_t)b * TT + 2) * TI;
    float* yp = y + (size_t)b * TT * TH;

    if (tid < TI / 4)
        *reinterpret_cast<float4*>(&xs[0][tid * 4]) =
            ld4(x + ((size_t)b * TT + 0) * TI + tid * 4);
    __syncthreads();
    if (tid < TI / 4)
        xreg = ld4(x + ((size_t)b * TT + 1) * TI + tid * 4);

#pragma unroll 1
    for (int t = 0; t < TT; ++t) {
        float4 acc = make_float4(0.f, 0.f, 0.f, 0.f);
#pragma unroll
        for (int k4 = 0; k4 < TH / 4; ++k4) {
            const float4 h4 = *reinterpret_cast<const float4*>(&h_lds[k4 * 4]);
            fma4(acc, w[k4], h4);
        }
        float p = hsum4(acc);
        {
            float4 fx = make_float4(0.f, 0.f, 0.f, 0.f);
            const float* xrow = xs[t & 1];
#pragma unroll
            for (int k4 = 0; k4 < TI / 4; ++k4) {
                const float4 x4 = *reinterpret_cast<const float4*>(&xrow[k4 * 4]);
                fma4(fx, u[k4], x4);
            }
            p += hsum4(fx) + bias;
        }

        const float act = (gate == 2) ? tanhf_fast(p) : sigf(p);
        g_lds[tid] = act;

        asm volatile("s_waitcnt lgkmcnt(0)" ::: "memory");
        __builtin_amdgcn_s_barrier();

        if (tid < TH) {
            const float gi = g_lds[j];
            const float gf = g_lds[TH + j];
            const float gg = g_lds[2 * TH + j];
            const float go = g_lds[3 * TH + j];
            c_state = fmaf(gf, c_state, gi * gg);
            h_keep  = go * tanhf_fast(c_state);
            h_lds[j] = h_keep;
            yp[(size_t)t * TH + j] = h_keep;
        }

        if (tid < TI / 4) {
            if (t + 1 < TT)
                *reinterpret_cast<float4*>(&xs[(t + 1) & 1][tid * 4]) = xreg;
            if (t + 2 < TT) xreg = ld4(xp + tid * 4);
        }
        xp += TI;

        asm volatile("s_waitcnt lgkmcnt(0)" ::: "memory");
        __builtin_amdgcn_s_barrier();
    }

    if (tid < TH) {
        hn[(size_t)b * TH + j] = h_keep;
        cn[(size_t)b * TH + j] = c_state;
    }
}

// ---------------------------------------------------------------------------
// BatchNorm over flattened [B*T, H] + LeakyReLU
// ---------------------------------------------------------------------------
__global__ void bn_zero(float* ws) { ws[threadIdx.x] = 0.0f; }

__global__ __launch_bounds__(256) void bn_stats(const float* __restrict__ y,
                                                float* __restrict__ ws)
{
    const int tid  = threadIdx.x;
    const int col4 = tid & 31;
    const int rg   = tid >> 5;
    const int NROW = TB * TT;
    float4 s = make_float4(0.f, 0.f, 0.f, 0.f);
    float4 q = make_float4(0.f, 0.f, 0.f, 0.f);
    for (int row = blockIdx.x * 8 + rg; row < NROW; row += gridDim.x * 8) {
        const float4 v = ld4(y + (size_t)row * TH + col4 * 4);
        s.x += v.x; s.y += v.y; s.z += v.z; s.w += v.w;
        q.x = fmaf(v.x, v.x, q.x); q.y = fmaf(v.y, v.y, q.y);
        q.z = fmaf(v.z, v.z, q.z); q.w = fmaf(v.w, v.w, q.w);
    }
    __shared__ float4 ls[256], lq[256];
    ls[tid] = s; lq[tid] = q;
    __syncthreads();
    if (tid < 32) {
        float4 S = ls[tid], Q = lq[tid];
        for (int g2 = 1; g2 < 8; ++g2) {
            const float4 a = ls[g2 * 32 + tid], b2 = lq[g2 * 32 + tid];
            S.x += a.x; S.y += a.y; S.z += a.z; S.w += a.w;
            Q.x += b2.x; Q.y += b2.y; Q.z += b2.z; Q.w += b2.w;
        }
        atomicAdd(&ws[tid * 4 + 0], S.x); atomicAdd(&ws[tid * 4 + 1], S.y);
        atomicAdd(&ws[tid * 4 + 2], S.z); atomicAdd(&ws[tid * 4 + 3], S.w);
        atomicAdd(&ws[TH + tid * 4 + 0], Q.x); atomicAdd(&ws[TH + tid * 4 + 1], Q.y);
        atomicAdd(&ws[TH + tid * 4 + 2], Q.z); atomicAdd(&ws[TH + tid * 4 + 3], Q.w);
    }
}

__global__ __launch_bounds__(256) void bn_apply(float* __restrict__ y,
                                                const float* __restrict__ ws,
                                                const float* __restrict__ gamma,
                                                const float* __restrict__ beta)
{
    const int tid  = threadIdx.x;
    const int col4 = tid & 31;
    const int rg   = tid >> 5;
    const int NROW = TB * TT;
    const float invN = 1.0f / (float)(TB * TT);

    const float4 sm = ld4(ws + col4 * 4);
    const float4 sq = ld4(ws + TH + col4 * 4);
    const float4 gm = ld4(gamma + col4 * 4);
    const float4 bt = ld4(beta + col4 * 4);
    float4 mean, scale, shift;
    mean.x = sm.x * invN; mean.y = sm.y * invN;
    mean.z = sm.z * invN; mean.w = sm.w * invN;
    scale.x = rsqrtf(fmaf(-mean.x, mean.x, sq.x * invN) + 1e-5f) * gm.x;
    scale.y = rsqrtf(fmaf(-mean.y, mean.y, sq.y * invN) + 1e-5f) * gm.y;
    scale.z = rsqrtf(fmaf(-mean.z, mean.z, sq.z * invN) + 1e-5f) * gm.z;
    scale.w = rsqrtf(fmaf(-mean.w, mean.w, sq.w * invN) + 1e-5f) * gm.w;
    shift.x = bt.x - mean.x * scale.x; shift.y = bt.y - mean.y * scale.y;
    shift.z = bt.z - mean.z * scale.z; shift.w = bt.w - mean.w * scale.w;

    for (int row = blockIdx.x * 8 + rg; row < NROW; row += gridDim.x * 8) {
        float* p = y + (size_t)row * TH + col4 * 4;
        float4 v = *reinterpret_cast<const float4*>(p);
        v.x = fmaf(v.x, scale.x, shift.x); v.y = fmaf(v.y, scale.y, shift.y);
        v.z = fmaf(v.z, scale.z, shift.z); v.w = fmaf(v.w, scale.w, shift.w);
        v.x = fmaxf(v.x, 0.01f * v.x); v.y = fmaxf(v.y, 0.01f * v.y);
        v.z = fmaxf(v.z, 0.01f * v.z); v.w = fmaxf(v.w, 0.01f * v.w);
        *reinterpret_cast<float4*>(p) = v;
    }
}

// ---------------------------------------------------------------------------
extern "C" void kernel_launch(void* const* d_in, const int* in_sizes, int n_in,
                              void* d_out, int out_size, void* d_ws, size_t ws_size,
                              hipStream_t stream)
{
    const float* x     = (const float*)d_in[0];
    const float* W_ih  = (const float*)d_in[1];
    const float* W_hh  = (const float*)d_in[2];
    const float* b_ih  = (const float*)d_in[3];
    const float* b_hh  = (const float*)d_in[4];
    const float* gamma = (const float*)d_in[5];
    const float* beta  = (const float*)d_in[6];

    float* y  = (float*)d_out;
    float* hn = y + (size_t)TB * TT * TH;
    float* cn = hn + TB * TH;

    float* ws_stats = (float*)d_ws;
    const size_t GX_BYTES = (size_t)TB * TT * TG * sizeof(float);
    const bool use_ws = ws_size >= GX_BYTES + 4096;

    bn_zero<<<1, 256, 0, stream>>>(ws_stats);

    if (use_ws) {
        float* gxbuf = (float*)((char*)d_ws + 4096);
        gx_precompute<<<2048, 256, 0, stream>>>(x, W_ih, b_ih, b_hh, gxbuf);
        lstm_scan_fp16<<<TB, 512, 0, stream>>>(W_hh, gxbuf, y, hn, cn);
    } else {
        lstm_scan_fused<<<TB, 512, 0, stream>>>(x, W_ih, W_hh, b_ih, b_hh,
                                                y, hn, cn);
    }

    bn_stats<<<512, 256, 0, stream>>>(y, ws_stats);
    bn_apply<<<2048, 256, 0, stream>>>(y, ws_stats, gamma, beta);
}